// Round 3
// baseline (30.168 us; speedup 1.0000x reference)
//
#include <hip/hip_runtime.h>
#include <math.h>

#define NN 27
#define KD 28
#define HD 8192
#define HA_ 256
#define NO_ 5
#define NPAIR (KD*HD)      // 229376
#define HB 8               // h-columns per block
#define NBLK (HD/HB)       // 1024 blocks -> 4 blocks/CU, 16 waves/CU

// ws: NBLK*KD partial-x floats (112 KB)

// One pass over W_lin. Thread t -> (k = t/8, hl = t%8); holds its 28 W values
// in VGPRs across the softmax phase so W_lin is read exactly once.
__global__ void __launch_bounds__(256, 4) kMain(const float* __restrict__ obs,
                                                const int* __restrict__ adj,
                                                const float* __restrict__ Wlin,
                                                const float* __restrict__ Wattn,
                                                const float* __restrict__ battn,
                                                float* __restrict__ ws) {
    __shared__ float P[HB][KD + 1];
    __shared__ float Q[HB][KD + 1];
    __shared__ float A[HB][KD];
    __shared__ unsigned adjm[NN];
    __shared__ float red[4][KD];

    const int t  = threadIdx.x;
    const int k  = t >> 3;            // 0..31 (k<28 active)
    const int hl = t & 7;
    const int h  = blockIdx.x * HB + hl;

    if (t < NN) {                     // pack adj column j into bits of adjm[j]
        unsigned m = 0;
        for (int i = 0; i < NN; ++i) m |= (adj[i * NN + t] != 0 ? 1u : 0u) << i;
        adjm[t] = m;
    }

    // ---- phase 1: load this thread's 28 W values (ONLY W_lin read), P/Q ----
    float4 wv[7];
    if (k < KD) {
        const float4* src = reinterpret_cast<const float4*>(
            Wlin + (size_t)k * NPAIR + (size_t)h * KD);
        const float4* wl4 = reinterpret_cast<const float4*>(Wattn);        // uniform -> scalar
        const float4* wr4 = reinterpret_cast<const float4*>(Wattn + KD);
#pragma unroll
        for (int f4 = 0; f4 < 7; ++f4) wv[f4] = src[f4];
        float p = 0.f, q = 0.f;
#pragma unroll
        for (int f4 = 0; f4 < 7; ++f4) {
            float4 wl = wl4[f4], wr = wr4[f4], w = wv[f4];
            p += w.x * wl.x + w.y * wl.y + w.z * wl.z + w.w * wl.w;
            q += w.x * wr.x + w.y * wr.y + w.z * wr.z + w.w * wr.w;
        }
        P[hl][k] = p;
        Q[hl][k] = q;
    }
    __syncthreads();

    // ---- phase 2: softmax row idx -> A[hl][j]  (threads 0..215) ----
    if (t < HB * NN) {
        const int hl2 = t / NN, j = t - hl2 * NN;
        int idx = 0;
        for (int n = NN - 1; n >= 0; --n) if (obs[n] != 0.f) idx = n;
        const float bias = battn[0];
        const float p27 = P[hl2][27], q27 = Q[hl2][27];
        const float sj = Q[hl2][j] + (j == 1 ? q27 : 0.f) + bias;
        const unsigned msk = adjm[j];
        float mx = -3.0e38f;
#pragma unroll
        for (int i = 0; i < NN; ++i) {
            float e = P[hl2][i] + (i == 1 ? p27 : 0.f) + sj;
            e = e >= 0.f ? e : 0.2f * e;
            if (((msk >> i) & 1) && e > mx) mx = e;
        }
        float den = 0.f, num = 0.f;
#pragma unroll
        for (int i = 0; i < NN; ++i) {
            float e = P[hl2][i] + (i == 1 ? p27 : 0.f) + sj;
            e = e >= 0.f ? e : 0.2f * e;
            float x = ((msk >> i) & 1) ? __expf(e - mx) : 0.f;
            den += x;
            if (i == idx) num = x;    // i static, idx runtime
        }
        A[hl2][j] = num / den;
    }
    __syncthreads();

    // ---- phase 3: acc[f] = b[k,h] * w[f] from registers; block-reduce ----
    float acc[KD];
    if (k < KD) {
        const float bk = A[hl][k < NN ? k : 1];   // emb = [I | (n==1)]
#pragma unroll
        for (int f4 = 0; f4 < 7; ++f4) {
            acc[4*f4+0] = bk * wv[f4].x;
            acc[4*f4+1] = bk * wv[f4].y;
            acc[4*f4+2] = bk * wv[f4].z;
            acc[4*f4+3] = bk * wv[f4].w;
        }
    } else {
#pragma unroll
        for (int f = 0; f < KD; ++f) acc[f] = 0.f;
    }
#pragma unroll
    for (int off = 32; off > 0; off >>= 1)
#pragma unroll
        for (int f = 0; f < KD; ++f) acc[f] += __shfl_xor(acc[f], off, 64);

    const int lane = t & 63, wv_id = t >> 6;
    if (lane == 0) {
#pragma unroll
        for (int f = 0; f < KD; ++f) red[wv_id][f] = acc[f];
    }
    __syncthreads();
    if (t < KD)
        ws[blockIdx.x * KD + t] = red[0][t] + red[1][t] + red[2][t] + red[3][t];
}

// reduce 1024 block-partials -> x, then MLP
__global__ void __launch_bounds__(512) kF(const float* __restrict__ W1,
                                          const float* __restrict__ b1,
                                          const float* __restrict__ W2,
                                          const float* __restrict__ b2,
                                          const float* __restrict__ ws,
                                          float* __restrict__ out) {
    __shared__ float xp[KD][16];
    __shared__ float x[KD];
    __shared__ float hh[HA_];
    const int t = threadIdx.x;
    if (t < 16 * KD) {
        const int seg = t / KD, f = t - seg * KD;
        float s = 0.f;
#pragma unroll 4
        for (int b = seg; b < NBLK; b += 16) s += ws[b * KD + f];
        xp[f][seg] = s;
    }
    __syncthreads();
    if (t < KD) {
        float s = 0.f;
#pragma unroll
        for (int g = 0; g < 16; ++g) s += xp[t][g];
        x[t] = s * (1.0f / HD);
    }
    __syncthreads();
    if (t < HA_) {
        float s = b1[t];
#pragma unroll
        for (int kk = 0; kk < KD; ++kk) s += x[kk] * W1[kk * HA_ + t];
        hh[t] = s >= 0.f ? s : 0.01f * s;
    }
    __syncthreads();
    if (t < NO_) {
        float s = b2[t];
        for (int u = 0; u < HA_; ++u) s += hh[u] * W2[u * NO_ + t];
        out[t] = s;
    }
}

extern "C" void kernel_launch(void* const* d_in, const int* in_sizes, int n_in,
                              void* d_out, int out_size, void* d_ws, size_t ws_size,
                              hipStream_t stream) {
    const float* obs   = (const float*)d_in[0];
    const int*   adj   = (const int*)  d_in[2];
    const float* Wlin  = (const float*)d_in[3];
    const float* Wattn = (const float*)d_in[4];
    const float* battn = (const float*)d_in[5];
    const float* W1    = (const float*)d_in[6];
    const float* b1    = (const float*)d_in[7];
    const float* W2    = (const float*)d_in[8];
    const float* b2    = (const float*)d_in[9];
    float* ws  = (float*)d_ws;
    float* out = (float*)d_out;

    kMain<<<NBLK, 256, 0, stream>>>(obs, adj, Wlin, Wattn, battn, ws);
    kF<<<1, 512, 0, stream>>>(W1, b1, W2, b2, ws, out);
}